// Round 9
// baseline (253.620 us; speedup 1.0000x reference)
//
#include <hip/hip_runtime.h>
#include <math.h>

// Shapes (fixed): q(8,256,128,128) c_t(8,256,512) W_a(512,256) W_p(256,512) V_p(2,256)
#define Bq 8
#define Tt 256
#define Dd 256
#define Hh 128
#define Ww 128
#define Cc 512
#define HW (Hh*Ww)
#define NBT (Bq*Tt)   // 2048 tokens

// ---------------- Kernel 0: transpose W_p (256x512) -> WpT (512x256) ------
__global__ __launch_bounds__(256) void transpose_wp(
    const float* __restrict__ W_p, float* __restrict__ WpT)
{
    __shared__ float tile[32][33];
    const int bx = blockIdx.x;            // c tile (16)
    const int by = blockIdx.y;            // p tile (8)
    const int lx = threadIdx.x & 31, ly = threadIdx.x >> 5;   // 32 x 8
#pragma unroll
    for (int j = 0; j < 4; j++) {
        int p = by * 32 + ly + j * 8;
        tile[ly + j * 8][lx] = W_p[(size_t)p * Cc + bx * 32 + lx];
    }
    __syncthreads();
#pragma unroll
    for (int j = 0; j < 4; j++) {
        int c = bx * 32 + ly + j * 8;
        WpT[(size_t)c * 256 + by * 32 + lx] = tile[lx][ly + j * 8];
    }
}

// ---------------- Kernel 1a: tiled GEMM, C = c_t @ [W_a | WpT], split-K x4
// r6 PMC showed all streaming-prep variants at 84% stall (VALUBusy 16%) —
// no LDS reuse, per-wave L2 streaming + readlane broadcasts. Canonical fix:
// LDS-tiled GEMM. 128x128 tile, BK=16, 8x8 micro (64 FMA : 4 ds_read_b128
// per k => VALU-bound), reg-staged next-step loads under 1024 FMAs.
// Grid 4(kq) x 16(mt) x 4(nt) = 256 blocks, 256 threads.
__global__ __launch_bounds__(256) void gemm_kernel(
    const float* __restrict__ c_t,   // (2048, 512)
    const float* __restrict__ W_a,   // (512, 256)
    const float* __restrict__ WpT,   // (512, 256)
    float* __restrict__ part)        // (4, 2048, 512) split-K partials
{
    __shared__ float As[16][132];    // [k][m], transposed store, +4 pad
    __shared__ float Bs[16][132];    // [k][n]

    const int tid = threadIdx.x;
    const int bid = blockIdx.x;
    const int kq = bid >> 6;                  // K-quarter 0..3
    const int mt = (bid >> 2) & 15;           // M-tile 0..15
    const int nt = bid & 3;                   // N-tile 0..3
    const int m0 = mt * 128;
    const int k0 = kq * 128;
    const float* Bmat = (nt < 2) ? (W_a + nt * 128) : (WpT + (nt - 2) * 128);

    const int tx = tid & 15, ty = tid >> 4;   // 16x16 thread grid
    const int sa_m = tid >> 2;                // 0..63 A-staging row
    const int sa_k = (tid & 3) * 4;           // 0,4,8,12
    const int sb_k = tid >> 4;                // 0..15 B-staging row
    const int sb_c = (tid & 15) * 4;          // 0..60

    float acc[8][8];
#pragma unroll
    for (int i = 0; i < 8; i++)
#pragma unroll
        for (int j = 0; j < 8; j++) acc[i][j] = 0.f;

    float4 ar0, ar1, br0, br1;
#define GLOAD(S) { \
        const float* Ab = c_t + (size_t)m0 * Cc + k0 + (S) * 16; \
        ar0 = *(const float4*)(Ab + (size_t)sa_m * Cc + sa_k); \
        ar1 = *(const float4*)(Ab + (size_t)(sa_m + 64) * Cc + sa_k); \
        const float* Bb = Bmat + (size_t)(k0 + (S) * 16) * 256; \
        br0 = *(const float4*)(Bb + (size_t)sb_k * 256 + sb_c); \
        br1 = *(const float4*)(Bb + (size_t)sb_k * 256 + sb_c + 64); }
#define SWRITE() { \
        As[sa_k + 0][sa_m] = ar0.x; As[sa_k + 1][sa_m] = ar0.y; \
        As[sa_k + 2][sa_m] = ar0.z; As[sa_k + 3][sa_m] = ar0.w; \
        As[sa_k + 0][sa_m + 64] = ar1.x; As[sa_k + 1][sa_m + 64] = ar1.y; \
        As[sa_k + 2][sa_m + 64] = ar1.z; As[sa_k + 3][sa_m + 64] = ar1.w; \
        *(float4*)&Bs[sb_k][sb_c] = br0; \
        *(float4*)&Bs[sb_k][sb_c + 64] = br1; }

    GLOAD(0)
    SWRITE()
    __syncthreads();

    for (int s = 0; s < 8; s++) {
        if (s < 7) GLOAD(s + 1)               // next-step loads fly under FMAs
#pragma unroll
        for (int k = 0; k < 16; k++) {
            const float4 a0 = *(const float4*)&As[k][ty * 8];
            const float4 a1 = *(const float4*)&As[k][ty * 8 + 4];
            const float4 b0 = *(const float4*)&Bs[k][tx * 8];
            const float4 b1 = *(const float4*)&Bs[k][tx * 8 + 4];
            const float a[8] = {a0.x, a0.y, a0.z, a0.w, a1.x, a1.y, a1.z, a1.w};
            const float b[8] = {b0.x, b0.y, b0.z, b0.w, b1.x, b1.y, b1.z, b1.w};
#pragma unroll
            for (int i = 0; i < 8; i++)
#pragma unroll
                for (int j = 0; j < 8; j++)
                    acc[i][j] = fmaf(a[i], b[j], acc[i][j]);
        }
        __syncthreads();
        if (s < 7) {
            SWRITE()
            __syncthreads();
        }
    }

    // store 128x128 partial tile
    float* P = part + ((size_t)kq * NBT + m0 + ty * 8) * 512 + nt * 128 + tx * 8;
#pragma unroll
    for (int i = 0; i < 8; i++) {
        *(float4*)(P + (size_t)i * 512)     = make_float4(acc[i][0], acc[i][1], acc[i][2], acc[i][3]);
        *(float4*)(P + (size_t)i * 512 + 4) = make_float4(acc[i][4], acc[i][5], acc[i][6], acc[i][7]);
    }
#undef GLOAD
#undef SWRITE
}

// ---------------- Kernel 1b: reduce split-K, u + p epilogue ---------------
// 256 blocks x 256 thr, 8 tokens/block. Sum 4 partials; col<256 -> u;
// col>=256 -> tanh*V_p staging -> butterfly p-reduce (4 waves x 4 jobs).
__global__ __launch_bounds__(256) void reduce_kernel(
    const float* __restrict__ part,  // (4, 2048, 512)
    const float* __restrict__ V_p,   // (2, 256)
    float* __restrict__ u_ws,        // (NBT, 256)
    float* __restrict__ p_ws)        // (NBT, 2)
{
    __shared__ float y0s[8][256];
    __shared__ float y1s[8][256];
    const int tid = threadIdx.x;
    const int ln  = tid & 63;
    const int m0  = blockIdx.x * 8;
    const float v0 = V_p[tid], v1 = V_p[256 + tid];

#pragma unroll
    for (int t = 0; t < 8; t++) {
        const size_t base = (size_t)(m0 + t) * 512 + tid;
        const float su = part[base]
                       + part[base + (size_t)1 * NBT * 512]
                       + part[base + (size_t)2 * NBT * 512]
                       + part[base + (size_t)3 * NBT * 512];
        const size_t basey = base + 256;
        const float sy = part[basey]
                       + part[basey + (size_t)1 * NBT * 512]
                       + part[basey + (size_t)2 * NBT * 512]
                       + part[basey + (size_t)3 * NBT * 512];
        u_ws[(size_t)(m0 + t) * Dd + tid] = su;
        const float th = tanhf(sy);
        y0s[t][tid] = th * v0;
        y1s[t][tid] = th * v1;
    }
    __syncthreads();

    const int wv = tid >> 6;                  // 0..3
#pragma unroll
    for (int jj = 0; jj < 4; jj++) {
        const int job  = wv * 4 + jj;         // 16 jobs = 8 tokens x 2 comps
        const int t    = job >> 1;
        const int comp = job & 1;
        const float* ys = comp ? &y1s[t][0] : &y0s[t][0];
        float s = ys[ln] + ys[ln + 64] + ys[ln + 128] + ys[ln + 192];
#pragma unroll
        for (int of = 32; of >= 1; of >>= 1) s += __shfl_xor(s, of);
        if (ln == 0)
            p_ws[(size_t)(m0 + t) * 2 + comp] = 128.f / (1.f + expf(-s));
    }
}

// ---------------- Kernel 2: register-resident window attention ------------
// (unchanged: 512 thr/token, window in registers, ~23 us, near its
//  ~18-20 us compulsory-fetch floor given poison-cold caches)
__global__ __launch_bounds__(512, 4) void attn_kernel(
    const float* __restrict__ q,     // (8,256,128,128)
    const float* __restrict__ u_ws,  // (NBT,256)
    const float* __restrict__ p_ws,  // (NBT,2)
    float* __restrict__ out)         // (NBT,256)
{
    __shared__ __align__(16) float pacc_s[16][9][12];   // 6912 B
    __shared__ __align__(16) float wpos[9][12];         // 432 B
    __shared__ float u_s[Dd];
    __shared__ float out_s[Dd];
    __shared__ float a_s[81];
    __shared__ float e_s[81];
    __shared__ float rex_s[9], cex_s[9];
    __shared__ int   rr_s[9], cc_s[9];
    __shared__ float m_sh, inv_sh;

    const int tid = threadIdx.x;
    int bt = blockIdx.x;
    bt = ((bt & 7) << 8) | (bt >> 3);    // batch b -> XCD b (L2 affinity)
    const int b = bt >> 8;

    if (tid < Dd) u_s[tid] = u_ws[(size_t)bt * Dd + tid];
    if (tid < 81) a_s[tid] = -INFINITY;          // prefill: unwritten = invalid

    if (tid < 18) {
        int   i = (tid < 9) ? tid : tid - 9;
        float p = p_ws[(size_t)bt * 2 + ((tid < 9) ? 0 : 1)];
        int base = (int)rintf(p);                 // round-half-even = jnp.round
        int v = base + i - 3;                     // round(p)+off+1, off=i-4
        v = min(max(v, 0), 129) % 129;
        float cl = (float)max(v - 1, 0);
        float z  = (cl - p) * 0.25f;
        float ex = -2.f * z * z;
        if (tid < 9) { rr_s[i] = v; rex_s[i] = ex; }
        else         { cc_s[i] = v; cex_s[i] = ex; }
    }
    __syncthreads();                              // (1)

    // Valid cols form one contiguous run: derive aligned load base (uniform).
    int jc0 = 0, c0 = 1;
#pragma unroll
    for (int j = 8; j >= 0; j--)
        if (cc_s[j] > 0) { jc0 = j; c0 = cc_s[j]; }
    const int cb = min((c0 - 1) & ~3, Ww - 12);   // 12-float window covers run
    const int e0 = (c0 - 1) - cb;

    // ---- gather into registers + fused partial scores ----
    const int g  = tid >> 5;                  // 0..15 d-group
    const int l5 = tid & 31;
    const bool lact = (l5 < 27);
    const int li = lact ? ((l5 * 171) >> 9) : 0;   // l5/3
    const int lv = l5 - li * 3;

    float4 xb[16];                            // the window slice, stays live
    if (lact) {
        const int vr = rr_s[li];
        const int rowoff = (max(vr, 1) - 1) * Ww + cb + 4 * lv;
        const float* qp = q + (size_t)b * Dd * HW + rowoff;
#pragma unroll
        for (int m = 0; m < 16; m++)
            xb[m] = *(const float4*)(qp + (size_t)(g + 16 * m) * HW);

        float px = 0.f, py = 0.f, pz = 0.f, pw = 0.f;
#pragma unroll
        for (int m = 0; m < 16; m++) {
            const float u = u_s[g + 16 * m];
            px = fmaf(xb[m].x, u, px); py = fmaf(xb[m].y, u, py);
            pz = fmaf(xb[m].z, u, pz); pw = fmaf(xb[m].w, u, pw);
        }
        *(float4*)&pacc_s[g][li][4 * lv] = make_float4(px, py, pz, pw);
    }
    __syncthreads();                              // (2)

    // ---- reduce partial scores over 16 d-groups, write valid a_s slots ----
    if (tid < 108) {
        const int lii = tid / 12;
        const int pos = tid - lii * 12;
        float s = 0.f;
#pragma unroll
        for (int gg = 0; gg < 16; gg++) s += pacc_s[gg][lii][pos];
        const int kj = pos - e0 + jc0;            // inverse of pos mapping
        if (kj >= 0 && kj < 9 && rr_s[lii] > 0 && cc_s[kj] > 0)
            a_s[lii * 9 + kj] = s;
    }
    __syncthreads();                              // (3)

    // ---- softmax over 81 (wave-0 butterfly) ----
    if (tid < 64) {
        float m = a_s[tid];
        if (tid + 64 < 81) m = fmaxf(m, a_s[tid + 64]);
        for (int o = 32; o >= 1; o >>= 1) m = fmaxf(m, __shfl_xor(m, o));
        if (tid == 0) m_sh = m;
    }
    __syncthreads();                              // (4)
    if (tid < 81) {
        const float av = a_s[tid];
        e_s[tid] = (av == -INFINITY) ? 0.f : expf(av - m_sh);
    }
    __syncthreads();                              // (5)
    if (tid < 64) {
        float sv = e_s[tid] + ((tid + 64 < 81) ? e_s[tid + 64] : 0.f);
        for (int o = 32; o >= 1; o >>= 1) sv += __shfl_xor(sv, o);
        if (tid == 0) inv_sh = 1.f / sv;
    }
    __syncthreads();                              // (6)

    // ---- dense position-weight tile: wpos[i][pos] (invalid = 0) ----
    if (tid < 108) {
        const int lii = tid / 12;
        const int pos = tid - lii * 12;
        const int kj  = pos - e0 + jc0;
        float w = 0.f;
        if (kj >= 0 && kj < 9 && rr_s[lii] > 0 && cc_s[kj] > 0)
            w = e_s[lii * 9 + kj] * inv_sh * expf(rex_s[lii] + cex_s[kj]);
        wpos[lii][pos] = w;
    }
    __syncthreads();                              // (7)

    // ---- pass 2: in-register FMA + half-group shuffle reduce ----
    float po[16];
    if (lact) {
        const float4 wv = *(const float4*)&wpos[li][4 * lv];
#pragma unroll
        for (int m = 0; m < 16; m++) {
            float acc = xb[m].x * wv.x;
            acc = fmaf(xb[m].y, wv.y, acc);
            acc = fmaf(xb[m].z, wv.z, acc);
            acc = fmaf(xb[m].w, wv.w, acc);
            po[m] = acc;
        }
    } else {
#pragma unroll
        for (int m = 0; m < 16; m++) po[m] = 0.f;
    }
#pragma unroll
    for (int o = 16; o >= 1; o >>= 1) {
#pragma unroll
        for (int m = 0; m < 16; m++) po[m] += __shfl_xor(po[m], o);
    }
    if (l5 == 0) {
#pragma unroll
        for (int m = 0; m < 16; m++) out_s[g + 16 * m] = po[m];
    }
    __syncthreads();                              // (8)
    if (tid < Dd) out[(size_t)bt * Dd + tid] = out_s[tid];
}

extern "C" void kernel_launch(void* const* d_in, const int* in_sizes, int n_in,
                              void* d_out, int out_size, void* d_ws, size_t ws_size,
                              hipStream_t stream) {
    const float* q   = (const float*)d_in[0];
    const float* c_t = (const float*)d_in[1];
    const float* W_a = (const float*)d_in[2];
    const float* W_p = (const float*)d_in[3];
    const float* V_p = (const float*)d_in[4];
    float* out  = (float*)d_out;
    float* u_ws = (float*)d_ws;                       // 2 MB
    float* p_ws = u_ws + (size_t)NBT * Dd;            // 16 KB
    float* WpT  = p_ws + (size_t)NBT * 2;             // 512 KB
    float* part = WpT + (size_t)Cc * 256;             // 16 MB

    transpose_wp<<<dim3(16, 8), 256, 0, stream>>>(W_p, WpT);
    gemm_kernel<<<256, 256, 0, stream>>>(c_t, W_a, WpT, part);
    reduce_kernel<<<256, 256, 0, stream>>>(part, V_p, u_ws, p_ws);
    attn_kernel<<<NBT, 512, 0, stream>>>(q, u_ws, p_ws, out);
}

// Round 10
// 248.133 us; speedup vs baseline: 1.0221x; 1.0221x over previous
//
#include <hip/hip_runtime.h>
#include <math.h>

// Shapes (fixed): q(8,256,128,128) c_t(8,256,512) W_a(512,256) W_p(256,512) V_p(2,256)
#define Bq 8
#define Tt 256
#define Dd 256
#define Hh 128
#define Ww 128
#define Cc 512
#define HW (Hh*Ww)
#define NBT (Bq*Tt)   // 2048 tokens

__device__ __forceinline__ float lane_bcast(float x, int l) {
    return __uint_as_float(__builtin_amdgcn_readlane(__float_as_uint(x), l));
}

// ---------------- Kernel 0: transpose W_p (256x512) -> WpT (512x256) ------
__global__ __launch_bounds__(256) void transpose_wp(
    const float* __restrict__ W_p, float* __restrict__ WpT)
{
    __shared__ float tile[32][33];
    const int bx = blockIdx.x;            // c tile (16)
    const int by = blockIdx.y;            // p tile (8)
    const int lx = threadIdx.x & 31, ly = threadIdx.x >> 5;   // 32 x 8
#pragma unroll
    for (int j = 0; j < 4; j++) {
        int p = by * 32 + ly + j * 8;
        tile[ly + j * 8][lx] = W_p[(size_t)p * Cc + bx * 32 + lx];
    }
    __syncthreads();
#pragma unroll
    for (int j = 0; j < 4; j++) {
        int c = bx * 32 + ly + j * 8;
        WpT[(size_t)c * 256 + by * 32 + lx] = tile[lx][ly + j * 8];
    }
}

// ---------------- Kernel 1: u = c_t@W_a, p_t = 128*sig(V_p tanh(W_p c)) ---
// Measured-best prep (r8): thread owns 4 output columns (float4 weight
// loads = 1KB/wave) x K-quarter (split-K x4 in block, ct fully
// register-resident, 1 readlane per 4 FMAs). Ping-pong 8-row chunks.
// 512 blocks, 2/CU, 4 waves/SIMD. 32KB LDS split-K reduce + p-epilogue.
// NOTE: five structurally distinct prep variants (r0/r7/r8/r5-fused/
// r9-tiled-GEMM) all land at 60-78us — duration is pinned by the harness
// poison-fill writeback shadow, not by kernel structure. This is the
// fastest measured variant (total 250.1us).
#define TOKP 4

#define LOAD8(BUF, BASE) \
    { _Pragma("unroll") for (int j = 0; j < 8; j++) \
        BUF[j] = *(const float4*)(Wk + (size_t)((BASE) + j) * 256); }

#define FMA8(BUF, BASE, CT) \
    { _Pragma("unroll") for (int j = 0; j < 8; j++) { \
        _Pragma("unroll") for (int t = 0; t < TOKP; t++) { \
            const float cv = lane_bcast(CT[t], ((BASE) + j) & 63); \
            acc[t].x = fmaf(cv, BUF[j].x, acc[t].x); \
            acc[t].y = fmaf(cv, BUF[j].y, acc[t].y); \
            acc[t].z = fmaf(cv, BUF[j].z, acc[t].z); \
            acc[t].w = fmaf(cv, BUF[j].w, acc[t].w); } } }

__global__ __launch_bounds__(512, 4) void prep_kernel(
    const float* __restrict__ c_t,   // (NBT, 512)
    const float* __restrict__ W_a,   // (512, 256)  [c][d]
    const float* __restrict__ WpT,   // (512, 256)  [c][p]
    const float* __restrict__ V_p,   // (2, 256)
    float* __restrict__ u_ws,        // (NBT, 256)
    float* __restrict__ p_ws)        // (NBT, 2)
{
    __shared__ __align__(16) float pacc_l[4][TOKP][512];   // 32 KB
    __shared__ float y0s[TOKP][256];                       // 4 KB
    __shared__ float y1s[TOKP][256];                       // 4 KB

    const int tid = threadIdx.x;
    const int ln  = tid & 63;
    const int kq  = tid >> 7;                // K-quarter 0..3
    const int mat = (tid >> 6) & 1;          // 0: W_a, 1: WpT
    const int cw  = ln << 2;                 // 4-col base within matrix
    const int bt0 = blockIdx.x * TOKP;

    const float* Wk  = (mat ? WpT : W_a) + cw + (size_t)(kq * 128) * 256;
    const float* ctb = c_t + (size_t)bt0 * Cc + kq * 128;

    // ct for this K-quarter, fully register-resident (2 regs/token)
    float ct0[TOKP], ct1[TOKP];
#pragma unroll
    for (int t = 0; t < TOKP; t++) {
        ct0[t] = ctb[t * Cc + ln];
        ct1[t] = ctb[t * Cc + 64 + ln];
    }

    float4 acc[TOKP];
#pragma unroll
    for (int t = 0; t < TOKP; t++) acc[t] = make_float4(0.f, 0.f, 0.f, 0.f);

    float4 wa[8], wb[8];
    LOAD8(wa, 0)
    LOAD8(wb, 8);   FMA8(wa, 0,   ct0)
    LOAD8(wa, 16);  FMA8(wb, 8,   ct0)
    LOAD8(wb, 24);  FMA8(wa, 16,  ct0)
    LOAD8(wa, 32);  FMA8(wb, 24,  ct0)
    LOAD8(wb, 40);  FMA8(wa, 32,  ct0)
    LOAD8(wa, 48);  FMA8(wb, 40,  ct0)
    LOAD8(wb, 56);  FMA8(wa, 48,  ct0)
    LOAD8(wa, 64);  FMA8(wb, 56,  ct0)
    LOAD8(wb, 72);  FMA8(wa, 64,  ct1)
    LOAD8(wa, 80);  FMA8(wb, 72,  ct1)
    LOAD8(wb, 88);  FMA8(wa, 80,  ct1)
    LOAD8(wa, 96);  FMA8(wb, 88,  ct1)
    LOAD8(wb, 104); FMA8(wa, 96,  ct1)
    LOAD8(wa, 112); FMA8(wb, 104, ct1)
    LOAD8(wb, 120); FMA8(wa, 112, ct1)
    FMA8(wb, 120, ct1)

    // split-K partials -> LDS (float4 stores, conflict-free)
#pragma unroll
    for (int t = 0; t < TOKP; t++)
        *(float4*)&pacc_l[kq][t][mat * 256 + cw] = acc[t];
    __syncthreads();

    // reduce 4 K-quarters; cols<256 -> u, cols>=256 -> tanh*V_p staging
#pragma unroll
    for (int i = 0; i < TOKP; i++) {
        const int col = tid & 511;               // == tid
        float s = pacc_l[0][i][col] + pacc_l[1][i][col]
                + pacc_l[2][i][col] + pacc_l[3][i][col];
        if (col < 256) {
            u_ws[(size_t)(bt0 + i) * Dd + col] = s;
        } else {
            const int o = col - 256;
            const float th = tanhf(s);
            y0s[i][o] = th * V_p[o];
            y1s[i][o] = th * V_p[256 + o];
        }
    }
    __syncthreads();

    // p_t: wave w -> token w&3, component w>>2
    const int wv = tid >> 6;
    const int tk = wv & 3;
    const float* ys = (wv >> 2) ? &y1s[tk][0] : &y0s[tk][0];
    float s = ys[ln] + ys[ln + 64] + ys[ln + 128] + ys[ln + 192];
#pragma unroll
    for (int of = 32; of >= 1; of >>= 1) s += __shfl_xor(s, of);
    if (ln == 0)
        p_ws[(size_t)(bt0 + tk) * 2 + (wv >> 2)] = 128.f / (1.f + expf(-s));
}

// ---------------- Kernel 2: register-resident window attention ------------
// 512 thr/token, window in registers (xb[16] float4), no LDS window
// buffer; ~23us, near its ~17-20us compulsory-fetch floor (106MB unique,
// poison-cold caches).
__global__ __launch_bounds__(512, 4) void attn_kernel(
    const float* __restrict__ q,     // (8,256,128,128)
    const float* __restrict__ u_ws,  // (NBT,256)
    const float* __restrict__ p_ws,  // (NBT,2)
    float* __restrict__ out)         // (NBT,256)
{
    __shared__ __align__(16) float pacc_s[16][9][12];   // 6912 B
    __shared__ __align__(16) float wpos[9][12];         // 432 B
    __shared__ float u_s[Dd];
    __shared__ float out_s[Dd];
    __shared__ float a_s[81];
    __shared__ float e_s[81];
    __shared__ float rex_s[9], cex_s[9];
    __shared__ int   rr_s[9], cc_s[9];
    __shared__ float m_sh, inv_sh;

    const int tid = threadIdx.x;
    int bt = blockIdx.x;
    bt = ((bt & 7) << 8) | (bt >> 3);    // batch b -> XCD b (L2 affinity)
    const int b = bt >> 8;

    if (tid < Dd) u_s[tid] = u_ws[(size_t)bt * Dd + tid];
    if (tid < 81) a_s[tid] = -INFINITY;          // prefill: unwritten = invalid

    if (tid < 18) {
        int   i = (tid < 9) ? tid : tid - 9;
        float p = p_ws[(size_t)bt * 2 + ((tid < 9) ? 0 : 1)];
        int base = (int)rintf(p);                 // round-half-even = jnp.round
        int v = base + i - 3;                     // round(p)+off+1, off=i-4
        v = min(max(v, 0), 129) % 129;
        float cl = (float)max(v - 1, 0);
        float z  = (cl - p) * 0.25f;
        float ex = -2.f * z * z;
        if (tid < 9) { rr_s[i] = v; rex_s[i] = ex; }
        else         { cc_s[i] = v; cex_s[i] = ex; }
    }
    __syncthreads();                              // (1)

    // Valid cols form one contiguous run: derive aligned load base (uniform).
    int jc0 = 0, c0 = 1;
#pragma unroll
    for (int j = 8; j >= 0; j--)
        if (cc_s[j] > 0) { jc0 = j; c0 = cc_s[j]; }
    const int cb = min((c0 - 1) & ~3, Ww - 12);   // 12-float window covers run
    const int e0 = (c0 - 1) - cb;

    // ---- gather into registers + fused partial scores ----
    const int g  = tid >> 5;                  // 0..15 d-group
    const int l5 = tid & 31;
    const bool lact = (l5 < 27);
    const int li = lact ? ((l5 * 171) >> 9) : 0;   // l5/3
    const int lv = l5 - li * 3;

    float4 xb[16];                            // the window slice, stays live
    if (lact) {
        const int vr = rr_s[li];
        const int rowoff = (max(vr, 1) - 1) * Ww + cb + 4 * lv;
        const float* qp = q + (size_t)b * Dd * HW + rowoff;
#pragma unroll
        for (int m = 0; m < 16; m++)
            xb[m] = *(const float4*)(qp + (size_t)(g + 16 * m) * HW);

        float px = 0.f, py = 0.f, pz = 0.f, pw = 0.f;
#pragma unroll
        for (int m = 0; m < 16; m++) {
            const float u = u_s[g + 16 * m];
            px = fmaf(xb[m].x, u, px); py = fmaf(xb[m].y, u, py);
            pz = fmaf(xb[m].z, u, pz); pw = fmaf(xb[m].w, u, pw);
        }
        *(float4*)&pacc_s[g][li][4 * lv] = make_float4(px, py, pz, pw);
    }
    __syncthreads();                              // (2)

    // ---- reduce partial scores over 16 d-groups, write valid a_s slots ----
    if (tid < 108) {
        const int lii = tid / 12;
        const int pos = tid - lii * 12;
        float s = 0.f;
#pragma unroll
        for (int gg = 0; gg < 16; gg++) s += pacc_s[gg][lii][pos];
        const int kj = pos - e0 + jc0;            // inverse of pos mapping
        if (kj >= 0 && kj < 9 && rr_s[lii] > 0 && cc_s[kj] > 0)
            a_s[lii * 9 + kj] = s;
    }
    __syncthreads();                              // (3)

    // ---- softmax over 81 (wave-0 butterfly) ----
    if (tid < 64) {
        float m = a_s[tid];
        if (tid + 64 < 81) m = fmaxf(m, a_s[tid + 64]);
        for (int o = 32; o >= 1; o >>= 1) m = fmaxf(m, __shfl_xor(m, o));
        if (tid == 0) m_sh = m;
    }
    __syncthreads();                              // (4)
    if (tid < 81) {
        const float av = a_s[tid];
        e_s[tid] = (av == -INFINITY) ? 0.f : expf(av - m_sh);
    }
    __syncthreads();                              // (5)
    if (tid < 64) {
        float sv = e_s[tid] + ((tid + 64 < 81) ? e_s[tid + 64] : 0.f);
        for (int o = 32; o >= 1; o >>= 1) sv += __shfl_xor(sv, o);
        if (tid == 0) inv_sh = 1.f / sv;
    }
    __syncthreads();                              // (6)

    // ---- dense position-weight tile: wpos[i][pos] (invalid = 0) ----
    if (tid < 108) {
        const int lii = tid / 12;
        const int pos = tid - lii * 12;
        const int kj  = pos - e0 + jc0;
        float w = 0.f;
        if (kj >= 0 && kj < 9 && rr_s[lii] > 0 && cc_s[kj] > 0)
            w = e_s[lii * 9 + kj] * inv_sh * expf(rex_s[lii] + cex_s[kj]);
        wpos[lii][pos] = w;
    }
    __syncthreads();                              // (7)

    // ---- pass 2: in-register FMA + half-group shuffle reduce ----
    float po[16];
    if (lact) {
        const float4 wv = *(const float4*)&wpos[li][4 * lv];
#pragma unroll
        for (int m = 0; m < 16; m++) {
            float acc = xb[m].x * wv.x;
            acc = fmaf(xb[m].y, wv.y, acc);
            acc = fmaf(xb[m].z, wv.z, acc);
            acc = fmaf(xb[m].w, wv.w, acc);
            po[m] = acc;
        }
    } else {
#pragma unroll
        for (int m = 0; m < 16; m++) po[m] = 0.f;
    }
#pragma unroll
    for (int o = 16; o >= 1; o >>= 1) {
#pragma unroll
        for (int m = 0; m < 16; m++) po[m] += __shfl_xor(po[m], o);
    }
    if (l5 == 0) {
#pragma unroll
        for (int m = 0; m < 16; m++) out_s[g + 16 * m] = po[m];
    }
    __syncthreads();                              // (8)
    if (tid < Dd) out[(size_t)bt * Dd + tid] = out_s[tid];
}

extern "C" void kernel_launch(void* const* d_in, const int* in_sizes, int n_in,
                              void* d_out, int out_size, void* d_ws, size_t ws_size,
                              hipStream_t stream) {
    const float* q   = (const float*)d_in[0];
    const float* c_t = (const float*)d_in[1];
    const float* W_a = (const float*)d_in[2];
    const float* W_p = (const float*)d_in[3];
    const float* V_p = (const float*)d_in[4];
    float* out  = (float*)d_out;
    float* u_ws = (float*)d_ws;                       // 2 MB
    float* p_ws = u_ws + (size_t)NBT * Dd;            // 16 KB
    float* WpT  = p_ws + (size_t)NBT * 2;             // 512 KB

    transpose_wp<<<dim3(16, 8), 256, 0, stream>>>(W_p, WpT);
    prep_kernel<<<NBT / TOKP, 512, 0, stream>>>(c_t, W_a, WpT, V_p, u_ws, p_ws);
    attn_kernel<<<NBT, 512, 0, stream>>>(q, u_ws, p_ws, out);
}